// Round 4
// baseline (326.231 us; speedup 1.0000x reference)
//
#include <hip/hip_runtime.h>
#include <stdint.h>

typedef short short8 __attribute__((ext_vector_type(8)));
typedef short short4v __attribute__((ext_vector_type(4)));
typedef float f32x4 __attribute__((ext_vector_type(4)));
typedef unsigned short ushort_t;

__device__ __forceinline__ unsigned short bf16_rne(float x){
  unsigned int u = __float_as_uint(x);
  return (unsigned short)((u + 0x7FFFu + ((u >> 16) & 1u)) >> 16);
}
__device__ __forceinline__ unsigned cvt_pk(float a, float b){
  unsigned r;
  asm("v_cvt_pk_bf16_f32 %0, %1, %2" : "=v"(r) : "v"(a), "v"(b));
  return r;
}
__device__ __forceinline__ void split4(float a0, float a1, float a2, float a3,
                                       unsigned &h0, unsigned &h1,
                                       unsigned &l0, unsigned &l1){
  h0 = cvt_pk(a0, a1); h1 = cvt_pk(a2, a3);
  float f0 = __uint_as_float(h0 << 16), f1 = __uint_as_float(h0 & 0xFFFF0000u);
  float f2 = __uint_as_float(h1 << 16), f3 = __uint_as_float(h1 & 0xFFFF0000u);
  l0 = cvt_pk(a0 - f0, a1 - f1); l1 = cvt_pk(a2 - f2, a3 - f3);
}
__device__ __forceinline__ uint4 hi8(float4 x, float4 y){
  uint4 h; h.x = cvt_pk(x.x, x.y); h.y = cvt_pk(x.z, x.w);
  h.z = cvt_pk(y.x, y.y); h.w = cvt_pk(y.z, y.w); return h;
}
__device__ __forceinline__ void split8(float4 x, float4 y, uint4 &h, uint4 &l){
  split4(x.x, x.y, x.z, x.w, h.x, h.y, l.x, l.y);
  split4(y.x, y.y, y.z, y.w, h.z, h.w, l.z, l.w);
}
__device__ __forceinline__ short8 comb(short4v a, short4v b){
  short8 r; r[0]=a[0]; r[1]=a[1]; r[2]=a[2]; r[3]=a[3];
  r[4]=b[0]; r[5]=b[1]; r[6]=b[2]; r[7]=b[3]; return r;
}

struct Pf { float4 v[4]; };
struct Ps { short8 v[2]; };

// ---------------- generic bt-GEMM ------------------------------------------
// C[m][n] = sum_k A[m][k]*B[n][k], both row-major.
// ABF/BBF: operand bf16 (1) or f32 fused-convert (0). NT=3: Markidis 3-term.
// EPI=1: +cvec[row]. OB=1: bf16 out. SWZ=1: out-GEMM XCD-swizzled 1D grid.
// Depth-2 register pipeline: each set reloads its next step right after its
// convert, 2 compute phases before consumption.
template<int ABF, int BBF, int NT, int EPI, int OB, int SWZ>
__global__ __launch_bounds__(256, 2) void gemm_bt(
    const void* __restrict__ Av, const void* __restrict__ Bv,
    void* __restrict__ Cv, const float* __restrict__ cvec,
    int tn, int kc, int lda, int ldb, int ldc,
    long sA, long sB, long sSl, long sC, long scv)
{
  int mt, nt, bz, ks;
  if (SWZ == 1){              // out-GEMM: grid 1024, tn=64, 4 mt-blocks/group
    int D = blockIdx.x; int x = D & 7, s = D >> 3;
    int g = x + 8 * (s >> 2); mt = s & 3; bz = g >> 6; nt = g & 63; ks = 0;
  } else {
    mt = blockIdx.x / tn; nt = blockIdx.x % tn; bz = blockIdx.y; ks = blockIdx.z;
  }
  const int m0 = mt << 7, n0 = nt << 7;
  const long kbeg = (long)ks * kc;

  constexpr int AL = (NT == 3) ? 8192 : 4096;
  __shared__ __align__(16) short Ah[AL];
  __shared__ __align__(16) short Bh2[AL];

  const int t = threadIdx.x;
  const int lane = t & 63, wid = t >> 6;
  const int rowS = t >> 1, kh = t & 1;
  const int wr = wid >> 1, wc = wid & 1;
  const int fr = lane & 15, fg = lane >> 4;

  f32x4 acc[4][4];
  const f32x4 Z = {0.f, 0.f, 0.f, 0.f};
  #pragma unroll
  for (int i = 0; i < 4; i++)
    #pragma unroll
    for (int j = 0; j < 4; j++) acc[i][j] = Z;

  const int wbase = rowS * 32;
  const int sw = (rowS >> 1) & 3;
  const int i0 = wbase + ((((kh << 1) + 0) ^ sw) << 3);
  const int i1 = wbase + ((((kh << 1) + 1) ^ sw) << 3);

  const float*    Afp = (const float*)Av    + sA * bz + (long)(m0 + rowS) * lda + kh * 16 + kbeg;
  const ushort_t* Abp = (const ushort_t*)Av + sA * bz + (long)(m0 + rowS) * lda + kh * 16 + kbeg;
  const float*    Bfp = (const float*)Bv    + sB * bz + (long)(n0 + rowS) * ldb + kh * 16 + kbeg;
  const ushort_t* Bbp = (const ushort_t*)Bv + sB * bz + (long)(n0 + rowS) * ldb + kh * 16 + kbeg;

  Pf A0f, A1f, B0f, B1f; Ps A0s, A1s, B0s, B1s;

  auto loadA = [&](Pf& f, Ps& s8, int kk){
    if (ABF == 0){
      const float4* p = (const float4*)(Afp + kk);
      f.v[0] = p[0]; f.v[1] = p[1]; f.v[2] = p[2]; f.v[3] = p[3];
    } else {
      const short8* p = (const short8*)(Abp + kk);
      s8.v[0] = p[0]; s8.v[1] = p[1];
    }
  };
  auto loadB = [&](Pf& f, Ps& s8, int kk){
    if (BBF == 0){
      const float4* p = (const float4*)(Bfp + kk);
      f.v[0] = p[0]; f.v[1] = p[1]; f.v[2] = p[2]; f.v[3] = p[3];
    } else {
      const short8* p = (const short8*)(Bbp + kk);
      s8.v[0] = p[0]; s8.v[1] = p[1];
    }
  };

  auto body = [&](Pf& Af, Ps& As8, Pf& Bf, Ps& Bs8, int kk){
    __syncthreads();
    if (ABF == 0){
      if (NT == 3){
        uint4 h0, h1, l0, l1;
        split8(Af.v[0], Af.v[1], h0, l0); split8(Af.v[2], Af.v[3], h1, l1);
        *(uint4*)&Ah[i0] = h0; *(uint4*)&Ah[i1] = h1;
        *(uint4*)&Ah[i0 + 4096] = l0; *(uint4*)&Ah[i1 + 4096] = l1;
      } else {
        *(uint4*)&Ah[i0] = hi8(Af.v[0], Af.v[1]); *(uint4*)&Ah[i1] = hi8(Af.v[2], Af.v[3]);
      }
    } else {
      *(short8*)&Ah[i0] = As8.v[0]; *(short8*)&Ah[i1] = As8.v[1];
    }
    if (BBF == 0){
      if (NT == 3){
        uint4 h0, h1, l0, l1;
        split8(Bf.v[0], Bf.v[1], h0, l0); split8(Bf.v[2], Bf.v[3], h1, l1);
        *(uint4*)&Bh2[i0] = h0; *(uint4*)&Bh2[i1] = h1;
        *(uint4*)&Bh2[i0 + 4096] = l0; *(uint4*)&Bh2[i1 + 4096] = l1;
      } else {
        *(uint4*)&Bh2[i0] = hi8(Bf.v[0], Bf.v[1]); *(uint4*)&Bh2[i1] = hi8(Bf.v[2], Bf.v[3]);
      }
    } else {
      *(short8*)&Bh2[i0] = Bs8.v[0]; *(short8*)&Bh2[i1] = Bs8.v[1];
    }
    __syncthreads();

    // reload this set with its own next step (+64), 2 phases ahead
    const int kn = (kk + 64 < kc) ? (kk + 64) : (kc - 32);
    loadA(Af, As8, kn); loadB(Bf, Bs8, kn);

    short8 fa[4], fb[4], fal[4], fbl[4];
    #pragma unroll
    for (int mi = 0; mi < 4; mi++){
      int r = wr * 64 + mi * 16 + fr;
      int idx = r * 32 + ((fg ^ ((r >> 1) & 3)) << 3);
      fa[mi] = *(const short8*)&Ah[idx];
      if (NT == 3) fal[mi] = *(const short8*)&Ah[idx + 4096];
    }
    #pragma unroll
    for (int ni = 0; ni < 4; ni++){
      int r = wc * 64 + ni * 16 + fr;
      int idx = r * 32 + ((fg ^ ((r >> 1) & 3)) << 3);
      fb[ni] = *(const short8*)&Bh2[idx];
      if (NT == 3) fbl[ni] = *(const short8*)&Bh2[idx + 4096];
    }
    #pragma unroll
    for (int mi = 0; mi < 4; mi++)
      #pragma unroll
      for (int ni = 0; ni < 4; ni++){
        acc[mi][ni] = __builtin_amdgcn_mfma_f32_16x16x32_bf16(fa[mi], fb[ni], acc[mi][ni], 0, 0, 0);
        if (NT == 3){
          acc[mi][ni] = __builtin_amdgcn_mfma_f32_16x16x32_bf16(fal[mi], fb[ni],  acc[mi][ni], 0, 0, 0);
          acc[mi][ni] = __builtin_amdgcn_mfma_f32_16x16x32_bf16(fa[mi],  fbl[ni], acc[mi][ni], 0, 0, 0);
        }
      }
  };

  loadA(A0f, A0s, 0);  loadB(B0f, B0s, 0);
  loadA(A1f, A1s, 32); loadB(B1f, B1s, 32);

  for (int kk = 0; kk < kc; kk += 64){
    body(A0f, A0s, B0f, B0s, kk);
    body(A1f, A1s, B1f, B1s, kk + 32);
  }

  float*    Cf = (float*)Cv    + sC * bz + sSl * ks;
  ushort_t* Cb = (ushort_t*)Cv + sC * bz;
  #pragma unroll
  for (int mi = 0; mi < 4; mi++)
    #pragma unroll
    for (int ni = 0; ni < 4; ni++){
      int gr0 = m0 + wr * 64 + mi * 16 + fg * 4;
      int gc  = n0 + wc * 64 + ni * 16 + fr;
      #pragma unroll
      for (int j = 0; j < 4; j++){
        float o = acc[mi][ni][j];
        if (EPI == 1) o += cvec[scv * bz + gr0 + j];
        if (OB == 1) Cb[(long)(gr0 + j) * ldc + gc] = bf16_rne(o);
        else         Cf[(long)(gr0 + j) * ldc + gc] = o;
      }
    }
}

// ---------------- GEMM1: Mt[b][kc][qc] = sum_s k[b][s][kc]*q[b][s][qc] ------
// split-K over 8 s-chunks; XCD-swizzled so the 16 tiles of one (sp,b) share
// an XCD (panels fit 4MB L2). Depth-2 register pipeline. Fused column sums.
__global__ __launch_bounds__(256, 2) void gemm1_tn(
    const float* __restrict__ q, const float* __restrict__ k,
    float* __restrict__ mtp, float* __restrict__ sqp, float* __restrict__ skp)
{
  // decode: xcd = D&7, group g = xcd + 8*((D>>3)>>4), tile = (D>>3)&15
  const int D = blockIdx.x;
  const int xg = D & 7, s = D >> 3;
  const int g = xg + 8 * (s >> 4), tile = s & 15;
  const int sp = g >> 2, b = g & 3;
  const int mt = tile >> 2, nt = tile & 3;

  const float* qb = q + (long)b * 8192 * 512;
  const float* kb = k + (long)b * 8192 * 512;

  __shared__ __align__(16) unsigned char As[16384];
  __shared__ __align__(16) unsigned char Bs[16384];

  const int t = threadIdx.x;
  const int lam = t & 31, sg = t >> 5;
  const int lane = t & 63, wid = t >> 6;
  const int wr = wid >> 1, wc = wid & 1;
  const int fr = lane & 15, fg = lane >> 4;

  f32x4 acc[4][4];
  const f32x4 Z = {0.f, 0.f, 0.f, 0.f};
  #pragma unroll
  for (int i = 0; i < 4; i++)
    #pragma unroll
    for (int j = 0; j < 4; j++) acc[i][j] = Z;

  float sumk4[4] = {0.f, 0.f, 0.f, 0.f};
  float sumq4[4] = {0.f, 0.f, 0.f, 0.f};

  int wA[4];
  #pragma unroll
  for (int j = 0; j < 4; j++){
    int c = lam * 4 + j;
    int swc = ((c >> 2) ^ ((c & 3) << 1)) & 7;
    wA[j] = c * 128 + ((sg ^ swc) << 4);
  }

  const float* kbase = kb + (long)(sp * 1024 + sg * 4) * 512 + mt * 128 + lam * 4;
  const float* qbase = qb + (long)(sp * 1024 + sg * 4) * 512 + nt * 128 + lam * 4;

  Pf K0, K1, Q0, Q1;

  auto ldK = [&](Pf& r, int st){
    const float* p = kbase + (long)st * 16384;
    r.v[0] = *(const float4*)(p);
    r.v[1] = *(const float4*)(p + 512);
    r.v[2] = *(const float4*)(p + 1024);
    r.v[3] = *(const float4*)(p + 1536);
  };
  auto ldQ = [&](Pf& r, int st){
    const float* p = qbase + (long)st * 16384;
    r.v[0] = *(const float4*)(p);
    r.v[1] = *(const float4*)(p + 512);
    r.v[2] = *(const float4*)(p + 1024);
    r.v[3] = *(const float4*)(p + 1536);
  };

  auto body = [&](Pf& Kc, Pf& Qc, int st){
    __syncthreads();
    #pragma unroll
    for (int j = 0; j < 4; j++){
      float a0 = ((const float*)&Kc.v[0])[j], a1 = ((const float*)&Kc.v[1])[j];
      float a2 = ((const float*)&Kc.v[2])[j], a3 = ((const float*)&Kc.v[3])[j];
      sumk4[j] += (a0 + a1) + (a2 + a3);
      unsigned h0, h1, l0, l1;
      split4(a0, a1, a2, a3, h0, h1, l0, l1);
      uint4 w; w.x = h0; w.y = h1; w.z = l0; w.w = l1;
      *(uint4*)(As + wA[j]) = w;
    }
    #pragma unroll
    for (int j = 0; j < 4; j++){
      float a0 = ((const float*)&Qc.v[0])[j], a1 = ((const float*)&Qc.v[1])[j];
      float a2 = ((const float*)&Qc.v[2])[j], a3 = ((const float*)&Qc.v[3])[j];
      sumq4[j] += (a0 + a1) + (a2 + a3);
      unsigned h0, h1, l0, l1;
      split4(a0, a1, a2, a3, h0, h1, l0, l1);
      uint4 w; w.x = h0; w.y = h1; w.z = l0; w.w = l1;
      *(uint4*)(Bs + wA[j]) = w;
    }
    __syncthreads();

    const int kn = (st + 2 <= 31) ? (st + 2) : 31;
    ldK(Kc, kn); ldQ(Qc, kn);

    short8 fa[4], fal[4], fb[4], fbl[4];
    #pragma unroll
    for (int mi = 0; mi < 4; mi++){
      int r = wr * 64 + mi * 16 + fr;
      int swc = ((r >> 2) ^ ((r & 3) << 1)) & 7;
      const unsigned char* bp = As + r * 128;
      int u0 = (((fg << 1) + 0) ^ swc) << 4;
      int u1 = (((fg << 1) + 1) ^ swc) << 4;
      fa[mi]  = comb(*(const short4v*)(bp + u0),     *(const short4v*)(bp + u1));
      fal[mi] = comb(*(const short4v*)(bp + u0 + 8), *(const short4v*)(bp + u1 + 8));
    }
    #pragma unroll
    for (int ni = 0; ni < 4; ni++){
      int r = wc * 64 + ni * 16 + fr;
      int swc = ((r >> 2) ^ ((r & 3) << 1)) & 7;
      const unsigned char* bp = Bs + r * 128;
      int u0 = (((fg << 1) + 0) ^ swc) << 4;
      int u1 = (((fg << 1) + 1) ^ swc) << 4;
      fb[ni]  = comb(*(const short4v*)(bp + u0),     *(const short4v*)(bp + u1));
      fbl[ni] = comb(*(const short4v*)(bp + u0 + 8), *(const short4v*)(bp + u1 + 8));
    }
    #pragma unroll
    for (int mi = 0; mi < 4; mi++)
      #pragma unroll
      for (int ni = 0; ni < 4; ni++){
        acc[mi][ni] = __builtin_amdgcn_mfma_f32_16x16x32_bf16(fa[mi],  fb[ni],  acc[mi][ni], 0, 0, 0);
        acc[mi][ni] = __builtin_amdgcn_mfma_f32_16x16x32_bf16(fal[mi], fb[ni],  acc[mi][ni], 0, 0, 0);
        acc[mi][ni] = __builtin_amdgcn_mfma_f32_16x16x32_bf16(fa[mi],  fbl[ni], acc[mi][ni], 0, 0, 0);
      }
  };

  ldK(K0, 0); ldQ(Q0, 0);
  ldK(K1, 1); ldQ(Q1, 1);

  for (int st = 0; st < 32; st += 2){
    body(K0, Q0, st);
    body(K1, Q1, st + 1);
  }

  float* Cp = mtp + ((long)sp * 4 + b) * (512 * 512);
  #pragma unroll
  for (int mi = 0; mi < 4; mi++)
    #pragma unroll
    for (int ni = 0; ni < 4; ni++){
      int gr0 = mt * 128 + wr * 64 + mi * 16 + fg * 4;
      int gc  = nt * 128 + wc * 64 + ni * 16 + fr;
      #pragma unroll
      for (int j = 0; j < 4; j++)
        Cp[(long)(gr0 + j) * 512 + gc] = acc[mi][ni][j];
    }

  __syncthreads();
  float* red = (float*)As;
  if (mt == 0){
    #pragma unroll
    for (int j = 0; j < 4; j++) red[sg * 128 + lam * 4 + j] = sumq4[j];
    __syncthreads();
    if (t < 128){
      float s2 = 0.f;
      #pragma unroll
      for (int gg = 0; gg < 8; gg++) s2 += red[gg * 128 + t];
      sqp[((long)b * 8 + sp) * 512 + nt * 128 + t] = s2;
    }
    __syncthreads();
  }
  if (nt == 0){
    #pragma unroll
    for (int j = 0; j < 4; j++) red[sg * 128 + lam * 4 + j] = sumk4[j];
    __syncthreads();
    if (t < 128){
      float s2 = 0.f;
      #pragma unroll
      for (int gg = 0; gg < 8; gg++) s2 += red[gg * 128 + t];
      skp[((long)b * 8 + sp) * 512 + mt * 128 + t] = s2;
    }
  }
}

// ---------------- small kernels ---------------------------------------------
__global__ __launch_bounds__(256) void reduceM(const float* __restrict__ p, float* __restrict__ o){
  const long i = ((long)blockIdx.x * 256 + threadIdx.x) * 4;
  float4 s = {0.f, 0.f, 0.f, 0.f};
  #pragma unroll
  for (int j = 0; j < 8; j++){
    float4 v = *(const float4*)(p + (long)j * 1048576 + i);
    s.x += v.x; s.y += v.y; s.z += v.z; s.w += v.w;
  }
  *(float4*)(o + i) = s;
}

// sum KS f32 slices; OB=1 -> bf16 output
template<int KS, int OB>
__global__ __launch_bounds__(256) void reduceS(const float* __restrict__ p, void* __restrict__ o, long sSl){
  const long i = ((long)blockIdx.x * 256 + threadIdx.x) * 4;
  float4 s = {0.f, 0.f, 0.f, 0.f};
  #pragma unroll
  for (int j = 0; j < KS; j++){
    float4 v = *(const float4*)(p + j * sSl + i);
    s.x += v.x; s.y += v.y; s.z += v.z; s.w += v.w;
  }
  if (OB == 1){
    uint2 r; r.x = cvt_pk(s.x, s.y); r.y = cvt_pk(s.z, s.w);
    *(uint2*)((ushort_t*)o + i) = r;
  } else {
    *(float4*)((float*)o + i) = s;
  }
}

__global__ __launch_bounds__(256) void transpose512(const float* __restrict__ in, float* __restrict__ outp){
  __shared__ float tile[32][33];
  const int bx = blockIdx.x & 15, by = blockIdx.x >> 4;
  const int tx = threadIdx.x & 31, ty = threadIdx.x >> 5;
  #pragma unroll
  for (int r = 0; r < 4; r++)
    tile[ty + 8*r][tx] = in[(long)(by*32 + ty + 8*r) * 512 + bx*32 + tx];
  __syncthreads();
  #pragma unroll
  for (int r = 0; r < 4; r++)
    outp[(long)(bx*32 + ty + 8*r) * 512 + by*32 + tx] = tile[tx][ty + 8*r];
}

__global__ __launch_bounds__(256) void smallprep(
    const float* __restrict__ sqp, const float* __restrict__ skp,
    const float* __restrict__ Wq, const float* __restrict__ Wk,
    float* __restrict__ wqsq, float* __restrict__ wksk)
{
  const int bid = blockIdx.x;
  const int tau = bid >> 4;
  const int b = (bid >> 2) & 3, ab = bid & 3;
  const float* P = tau ? skp : sqp;
  const float* W = tau ? Wk : Wq;
  float* O = tau ? wksk : wqsq;
  __shared__ float sv[512];
  const int t = threadIdx.x;
  for (int i = t; i < 512; i += 256){
    float s = 0.f;
    #pragma unroll
    for (int g = 0; g < 8; g++) s += P[((long)b * 8 + g) * 512 + i];
    sv[i] = s;
  }
  __syncthreads();
  const int a = ab * 128 + (t >> 1), half = t & 1;
  const float* Wr = W + (long)a * 512 + half * 256;
  const float* sp2 = sv + half * 256;
  float d = 0.f;
  #pragma unroll 8
  for (int j = 0; j < 256; j++) d += Wr[j] * sp2[j];
  d += __shfl_xor(d, 1);
  if (!half) O[(long)b * 512 + a] = d;
}

__global__ __launch_bounds__(256) void softmax_k(
    const float* __restrict__ num, float* __restrict__ attn, float* __restrict__ cv,
    const float* __restrict__ wqsq, const float* __restrict__ wksk,
    const float* __restrict__ bq, const float* __restrict__ bk,
    const float* __restrict__ bv, const int* __restrict__ gt)
{
  const int a = blockIdx.x, b = blockIdx.y;
  const int t = threadIdx.x;
  const int lane = t & 63, wid = t >> 6;
  __shared__ unsigned char gf[512];
  __shared__ float red[4];
  gf[t] = 0; gf[t + 256] = 0;
  __syncthreads();
  if (t < 64) gf[gt[t]] = 1;
  __syncthreads();

  const float* row = num + ((long)b * 512 + a) * 512;
  const float bqa = bq[a], wqa = wqsq[b * 512 + a];
  const int ga = gf[a];
  const int c0 = t, c1 = t + 256;
  float l0 = (row[c0] + wqa * bk[c0] + bqa * wksk[b*512 + c0] + 8192.0f * bqa * bk[c0]) * 0.04419417382415922f;
  float l1 = (row[c1] + wqa * bk[c1] + bqa * wksk[b*512 + c1] + 8192.0f * bqa * bk[c1]) * 0.04419417382415922f;
  if (a < c0 && !ga && !gf[c0]) l0 = -1e30f;
  if (a < c1 && !ga && !gf[c1]) l1 = -1e30f;

  float m = fmaxf(l0, l1);
  #pragma unroll
  for (int o = 32; o; o >>= 1) m = fmaxf(m, __shfl_xor(m, o));
  if (lane == 0) red[wid] = m;
  __syncthreads();
  m = fmaxf(fmaxf(red[0], red[1]), fmaxf(red[2], red[3]));
  __syncthreads();

  float e0 = __expf(l0 - m), e1 = __expf(l1 - m);
  float s = e0 + e1;
  #pragma unroll
  for (int o = 32; o; o >>= 1) s += __shfl_xor(s, o);
  if (lane == 0) red[wid] = s;
  __syncthreads();
  s = red[0] + red[1] + red[2] + red[3];
  __syncthreads();
  const float inv = 1.0f / s;
  const float a0 = e0 * inv, a1 = e1 * inv;
  float* arow = attn + ((long)b * 512 + a) * 512;
  arow[c0] = a0; arow[c1] = a1;

  float cp = a0 * bv[c0] + a1 * bv[c1];
  #pragma unroll
  for (int o = 32; o; o >>= 1) cp += __shfl_xor(cp, o);
  if (lane == 0) red[wid] = cp;
  __syncthreads();
  if (t == 0) cv[(long)b * 512 + a] = red[0] + red[1] + red[2] + red[3];
}

// ---------------- launch -----------------------------------------------------
extern "C" void kernel_launch(void* const* d_in, const int* in_sizes, int n_in,
                              void* d_out, int out_size, void* d_ws, size_t ws_size,
                              hipStream_t stream) {
  const float* q  = (const float*)d_in[0];
  const float* k  = (const float*)d_in[1];
  const float* v  = (const float*)d_in[2];
  const float* Wq = (const float*)d_in[3];
  const float* bq = (const float*)d_in[4];
  const float* Wk = (const float*)d_in[5];
  const float* bk = (const float*)d_in[6];
  const float* Wv = (const float*)d_in[7];
  const float* bv = (const float*)d_in[8];
  const int*   gt = (const int*)d_in[9];
  float* out = (float*)d_out;

  float* w = (float*)d_ws;
  // region [0, 32MB): gemm1 partial slices; later reused for mid-GEMM k-slices
  float* mtp  = w;                      // 8 x 1048576 f32
  float* slc  = w;                      // 4 x 1048576 f32 (mid-GEMM partials)
  float* mt   = w + 8388608;            // 1048576
  float* t1   = w + 9437184;            // 1048576
  float* numb = w + 9699328;            // 1048576 -- wait, keep 1M spacing
  float* attn = w + 10485760;           // placed below with full spacing
  // use clean 1M-float spacing to avoid mistakes:
  mt   = w + 8388608;                   // [8M, 9M)
  t1   = w + 9437184;                   // [9M+256K... ] -- replaced below
  // final layout (floats):
  float* MT   = w + 8388608;            // 1048576
  float* T1   = MT  + 1048576;          // 1048576
  float* NUM  = T1  + 1048576;          // 1048576
  float* ATT  = NUM + 1048576;          // 1048576
  float* A2H  = ATT + 1048576;          // 524288 f32 = 1M ushorts
  float* WVT  = A2H + 524288;           // 262144
  float* SQP  = WVT + 262144;           // 16384
  float* SKP  = SQP + 16384;            // 16384
  float* WQS  = SKP + 16384;            // 2048
  float* WKS  = WQS + 2048;             // 2048
  float* CV   = WKS + 2048;             // 2048
  ushort_t* a2h = (ushort_t*)A2H;
  (void)mtp; (void)mt; (void)t1; (void)numb; (void)attn;

  transpose512<<<256, 256, 0, stream>>>(Wv, WVT);
  gemm1_tn<<<512, 256, 0, stream>>>(q, k, w, SQP, SKP);
  reduceM<<<1024, 256, 0, stream>>>(w, MT);
  smallprep<<<32, 256, 0, stream>>>(SQP, SKP, Wq, Wk, WQS, WKS);
  // T1[a][j] = sum_i Wq[a][i] * MT[j][i]   (split-K 4)
  gemm_bt<0,0,3,0,0,0><<<dim3(16, 4, 4), 256, 0, stream>>>(Wq, MT, slc, nullptr,
      4, 128, 512, 512, 512, 0L, 262144L, 1048576L, 262144L, 0L);
  reduceS<4,0><<<1024, 256, 0, stream>>>(slc, T1, 1048576L);
  // NUM[a][c] = sum_j T1[a][j] * Wk[c][j]  (split-K 4)
  gemm_bt<0,0,3,0,0,0><<<dim3(16, 4, 4), 256, 0, stream>>>(T1, Wk, slc, nullptr,
      4, 128, 512, 512, 512, 262144L, 0L, 1048576L, 262144L, 0L);
  reduceS<4,0><<<1024, 256, 0, stream>>>(slc, NUM, 1048576L);
  softmax_k<<<dim3(512, 4), 256, 0, stream>>>(NUM, ATT, CV, WQS, WKS, bq, bk, bv, gt);
  // A2[a][i] = sum_c attn[a][c] * WvT[i][c] (split-K 4) -> bf16 after reduce
  gemm_bt<0,0,1,0,0,0><<<dim3(16, 4, 4), 256, 0, stream>>>(ATT, WVT, slc, nullptr,
      4, 128, 512, 512, 512, 262144L, 0L, 1048576L, 262144L, 0L);
  reduceS<4,1><<<1024, 256, 0, stream>>>(slc, a2h, 1048576L);
  // out[a][s] = sum_i A2[a][i] * v[s][i] + cv[a]  (A bf16, XCD-swizzled)
  gemm_bt<1,0,1,1,0,1><<<1024, 256, 0, stream>>>(a2h, v, out, CV,
      64, 512, 512, 512, 8192, 262144L, 4194304L, 0L, 4194304L, 512L);
}